// Round 4
// baseline (21633.525 us; speedup 1.0000x reference)
//
#include <hip/hip_runtime.h>
#include <math.h>

// Problem constants (reference: B,T,D,H = 32,2048,512,512)
#define BB   32
#define TT   2048
#define DD   512
#define HH   512
#define G4H  2048   // 4*H

// ---------------------------------------------------------------------------
// Phase A: xw[t_local*32 + b][col] = sum_d X[b][t0+t][d] * W[d][col] + bias[col]
// fp32 tiled GEMM: 128x128 block tile, 16 K-step, 256 threads, 8x8 microtile.
// Also zeroes the 8 group barrier counters on the first chunk (t0==0).
// ---------------------------------------------------------------------------
__global__ __launch_bounds__(256, 2) void gemm_xw(
    const float* __restrict__ X, const float* __restrict__ Wm,
    const float* __restrict__ bias, float* __restrict__ xw,
    int t0, unsigned int* __restrict__ ctr)
{
    if (t0 == 0 && blockIdx.x == 0 && blockIdx.y == 0 && threadIdx.x < 8)
        ctr[threadIdx.x * 64] = 0u;

    __shared__ float As[16][128];
    __shared__ float Bs[16][128];

    const int tid  = threadIdx.x;
    const int row0 = blockIdx.y * 128;   // rows: (t_local, b) t-major
    const int col0 = blockIdx.x * 128;
    const int tx = tid & 15;
    const int ty = tid >> 4;

    float acc[8][8];
    #pragma unroll
    for (int i = 0; i < 8; ++i)
        #pragma unroll
        for (int j = 0; j < 8; ++j) acc[i][j] = 0.f;

    for (int k0 = 0; k0 < DD; k0 += 16) {
        #pragma unroll
        for (int i = 0; i < 2; ++i) {
            int qa = tid + i * 256;          // 0..511 quads
            int r  = qa >> 2, kq = qa & 3;
            int grow = row0 + r;
            int b = grow & 31, tl = grow >> 5;
            const float4 a = *(const float4*)(X + ((size_t)b * TT + t0 + tl) * DD + k0 + kq * 4);
            As[kq*4+0][r] = a.x; As[kq*4+1][r] = a.y;
            As[kq*4+2][r] = a.z; As[kq*4+3][r] = a.w;

            int qb = tid + i * 256;
            int kb = qb >> 5, c4 = qb & 31;
            *(float4*)&Bs[kb][c4*4] =
                *(const float4*)(Wm + (size_t)(k0 + kb) * G4H + col0 + c4 * 4);
        }
        __syncthreads();

        #pragma unroll
        for (int k = 0; k < 16; ++k) {
            float a[8], b[8];
            #pragma unroll
            for (int i = 0; i < 8; ++i) a[i] = As[k][ty*8 + i];
            #pragma unroll
            for (int j = 0; j < 8; ++j) b[j] = Bs[k][tx*8 + j];
            #pragma unroll
            for (int i = 0; i < 8; ++i)
                #pragma unroll
                for (int j = 0; j < 8; ++j) acc[i][j] += a[i] * b[j];
        }
        __syncthreads();
    }

    #pragma unroll
    for (int i = 0; i < 8; ++i) {
        int grow = row0 + ty*8 + i;
        float* dst = xw + (size_t)grow * G4H + col0 + tx*8;
        #pragma unroll
        for (int j = 0; j < 8; j += 4) {
            float4 v;
            v.x = acc[i][j+0] + bias[col0 + tx*8 + j + 0];
            v.y = acc[i][j+1] + bias[col0 + tx*8 + j + 1];
            v.z = acc[i][j+2] + bias[col0 + tx*8 + j + 2];
            v.w = acc[i][j+3] + bias[col0 + tx*8 + j + 3];
            *(float4*)(dst + j) = v;
        }
    }
}

// ---------------------------------------------------------------------------
// Phase B: persistent recurrent kernel, LDS-resident weights.
// Grid = 256 blocks x 256 threads. p = blockIdx%8 (batches 4p..4p+3),
// q = blockIdx/8 (hidden units 16q..16q+15 -> 64 gate columns, col_local=lane).
// Wave w (0..3) = K-slice of 128 (compute) = batch (reduce/update).
// Recurrent W slice (512 x 64 cols = 128 KiB) lives in LDS, k-packed as
// float4 wlds[k>>2][col]: the dot's weight read is a contiguous stride-1
// ds_read_b128 (conflict-free), loaded from global ONCE per dispatch.
// This removes the per-step L2-latency chain the compiler created by
// rematerializing weight loads in R1-R3 (VGPR fight abandoned).
// LDS total = 128K (w) + 8K (hbuf) + 4K (red) = 140 KiB -> 1 block/CU.
// ---------------------------------------------------------------------------
__global__ __launch_bounds__(256, 1) void lstm_rec(
    const float* __restrict__ W,
    const float* __restrict__ h_init,
    const float* __restrict__ xw,
    float* __restrict__ out,
    float* __restrict__ c_ws,
    unsigned int* __restrict__ ctr,
    int t0, int nT)
{
    __shared__ float4 wlds[128][64];    // [k>>2][col_local] = w[4k..4k+3][col]
    __shared__ float  hbuf[4][HH];      // h for the 4 batches of this group
    __shared__ float  red[4][4][64];    // [kslice-wave][batch][lane]

    const int tid  = threadIdx.x;
    const int p    = blockIdx.x & 7;
    const int q    = blockIdx.x >> 3;
    const int w    = tid >> 6;          // wave id = K-slice (compute) = batch (reduce)
    const int lane = tid & 63;
    const int gi   = lane >> 4;
    const int u    = lane & 15;
    const int col  = gi * HH + q * 16 + u;   // this lane's global gate column

    // One-time: stage this block's recurrent W slice into LDS, k-packed.
    // Thread (cc = tid&63, kq = tid>>6) fills wlds[i*4+kq][cc].
    {
        const int cc = tid & 63;
        const int kq = tid >> 6;
        const int cg = (cc >> 4) * HH + q * 16 + (cc & 15);  // global col of cc
        const float* Wr = W + (size_t)DD * G4H + cg;
        #pragma unroll 4
        for (int i = 0; i < 32; ++i) {
            const int k4 = i * 4 + kq;          // 0..127
            float4 v;
            v.x = Wr[(size_t)(4 * k4 + 0) * G4H];
            v.y = Wr[(size_t)(4 * k4 + 1) * G4H];
            v.z = Wr[(size_t)(4 * k4 + 2) * G4H];
            v.w = Wr[(size_t)(4 * k4 + 3) * G4H];
            wlds[k4][cc] = v;
        }
    }
    __syncthreads();

    // c state: lanes 0..15 of wave w hold c[batch 4p+w][unit q*16+lane]
    float c = 0.f;
    if (t0 > 0 && lane < 16)
        c = c_ws[(size_t)(4 * p + w) * HH + q * 16 + lane];

    unsigned int* myctr = ctr + p * 64;
    const int k4b = w * 32;               // this wave's k-slice, in float4 units

    for (int t = 0; t < nT; ++t) {
        const int gt = t0 + t;

        // Issue the precomputed x-part load early (independent of staging).
        const float xg = xw[((size_t)t * BB + 4 * p + w) * G4H + col];

        // Stage h(gt-1) into LDS: 4 x 512 floats, 2 float4 per thread.
        #pragma unroll
        for (int i = 0; i < 2; ++i) {
            int qd = tid + i * 256;          // 0..511
            int b  = qd >> 7, k4 = qd & 127;
            const float* src = (gt == 0)
                ? (h_init + k4 * 4)
                : (out + ((size_t)(4 * p + b) * TT + (gt - 1)) * HH + k4 * 4);
            *(float4*)&hbuf[b][k4 * 4] = *(const float4*)src;
        }
        __syncthreads();

        // K-slice partial dot: a[b] += sum_k w[k][col] * h[b][k], k in slice w.
        const float4* hb0 = (const float4*)&hbuf[0][w * 128];
        const float4* hb1 = (const float4*)&hbuf[1][w * 128];
        const float4* hb2 = (const float4*)&hbuf[2][w * 128];
        const float4* hb3 = (const float4*)&hbuf[3][w * 128];

        float a0 = 0.f, a1 = 0.f, a2 = 0.f, a3 = 0.f;
        #pragma unroll
        for (int j = 0; j < 32; ++j) {
            const float4 wv = wlds[k4b + j][lane];   // contiguous b128, no conflict
            const float4 h0 = hb0[j];                // uniform broadcast reads
            const float4 h1 = hb1[j];
            const float4 h2 = hb2[j];
            const float4 h3 = hb3[j];
            a0 += wv.x*h0.x; a0 += wv.y*h0.y; a0 += wv.z*h0.z; a0 += wv.w*h0.w;
            a1 += wv.x*h1.x; a1 += wv.y*h1.y; a1 += wv.z*h1.z; a1 += wv.w*h1.w;
            a2 += wv.x*h2.x; a2 += wv.y*h2.y; a2 += wv.z*h2.z; a2 += wv.w*h2.w;
            a3 += wv.x*h3.x; a3 += wv.y*h3.y; a3 += wv.z*h3.z; a3 += wv.w*h3.w;
        }

        red[w][0][lane] = a0; red[w][1][lane] = a1;
        red[w][2][lane] = a2; red[w][3][lane] = a3;
        __syncthreads();

        // Wave w reduces batch w across the 4 K-slices, adds x-part (+bias).
        float g = red[0][w][lane] + red[1][w][lane]
                + red[2][w][lane] + red[3][w][lane] + xg;

        // Gather f,i,o,g for unit ul; lanes 0..15 do the elementwise update.
        const int ul = lane & 15;
        const float fv = __shfl(g, ul);
        const float iv = __shfl(g, ul + 16);
        const float ov = __shfl(g, ul + 32);
        const float gv = __shfl(g, ul + 48);
        if (lane < 16) {
            const float sf = 1.f / (1.f + __expf(-fv));
            const float si = 1.f / (1.f + __expf(-iv));
            const float so = 1.f / (1.f + __expf(-ov));
            const float tg = 1.f - 2.f / (__expf(2.f * gv) + 1.f);
            c = sf * c + si * tg;
            const float tc = 1.f - 2.f / (__expf(2.f * c) + 1.f);
            const float h = so * tc;
            out[((size_t)(4 * p + w) * TT + gt) * HH + q * 16 + lane] = h;
        }

        // Per-group barrier: 32 blocks. Release publishes h writes; acquire
        // invalidates stale lines before next step's h reads.
        __syncthreads();
        if (tid == 0) {
            __hip_atomic_fetch_add(myctr, 1u, __ATOMIC_RELEASE, __HIP_MEMORY_SCOPE_AGENT);
            const unsigned int tgt = 32u * (unsigned int)(gt + 1);
            while (__hip_atomic_load(myctr, __ATOMIC_ACQUIRE, __HIP_MEMORY_SCOPE_AGENT) < tgt) {}
        }
        __syncthreads();
    }

    // Spill c state for the next chunk.
    if (lane < 16)
        c_ws[(size_t)(4 * p + w) * HH + q * 16 + lane] = c;
}

// ---------------------------------------------------------------------------
extern "C" void kernel_launch(void* const* d_in, const int* in_sizes, int n_in,
                              void* d_out, int out_size, void* d_ws, size_t ws_size,
                              hipStream_t stream) {
    const float* x      = (const float*)d_in[0];
    // d_in[1] = input_paddings (unused)
    const float* W      = (const float*)d_in[2];
    const float* bias   = (const float*)d_in[3];
    const float* h_init = (const float*)d_in[4];
    float* out = (float*)d_out;

    // Pick the largest chunk of T whose xw buffer fits in ws
    // (xw chunk = CT*32*2048*4 bytes; + 2KB counters + 64KB c-state).
    static const int cand[] = {2048, 1024, 512, 256, 128, 64, 32, 16, 8, 4};
    int CT = 4;
    for (int i = 0; i < 10; ++i) {
        if ((size_t)cand[i] * BB * G4H * 4 + 2048 + 65536 <= ws_size) { CT = cand[i]; break; }
    }
    const size_t xw_bytes = (size_t)CT * BB * G4H * 4;
    float*        xw   = (float*)d_ws;
    unsigned int* ctr  = (unsigned int*)((char*)d_ws + xw_bytes);
    float*        c_ws = (float*)((char*)d_ws + xw_bytes + 2048);

    for (int t0 = 0; t0 < TT; t0 += CT) {
        dim3 g(G4H / 128, CT * BB / 128);
        gemm_xw<<<g, 256, 0, stream>>>(x, W, bias, xw, t0, ctr);
        lstm_rec<<<256, 256, 0, stream>>>(W, h_init, xw, out, c_ws, ctr, t0, CT);
    }
}

// Round 5
// 20287.173 us; speedup vs baseline: 1.0664x; 1.0664x over previous
//
#include <hip/hip_runtime.h>
#include <math.h>

// Problem constants (reference: B,T,D,H = 32,2048,512,512)
#define BB   32
#define TT   2048
#define DD   512
#define HH   512
#define G4H  2048   // 4*H

// ---------------------------------------------------------------------------
// Phase A: xw[t_local*32 + b][col] = sum_d X[b][t0+t][d] * W[d][col] + bias[col]
// fp32 tiled GEMM: 128x128 block tile, 16 K-step, 256 threads, 8x8 microtile.
// Also zeroes the 8 group barrier counters on the first chunk (t0==0).
// ---------------------------------------------------------------------------
__global__ __launch_bounds__(256, 2) void gemm_xw(
    const float* __restrict__ X, const float* __restrict__ Wm,
    const float* __restrict__ bias, float* __restrict__ xw,
    int t0, unsigned int* __restrict__ ctr)
{
    if (t0 == 0 && blockIdx.x == 0 && blockIdx.y == 0 && threadIdx.x < 8)
        ctr[threadIdx.x * 64] = 0u;

    __shared__ float As[16][128];
    __shared__ float Bs[16][128];

    const int tid  = threadIdx.x;
    const int row0 = blockIdx.y * 128;   // rows: (t_local, b) t-major
    const int col0 = blockIdx.x * 128;
    const int tx = tid & 15;
    const int ty = tid >> 4;

    float acc[8][8];
    #pragma unroll
    for (int i = 0; i < 8; ++i)
        #pragma unroll
        for (int j = 0; j < 8; ++j) acc[i][j] = 0.f;

    for (int k0 = 0; k0 < DD; k0 += 16) {
        #pragma unroll
        for (int i = 0; i < 2; ++i) {
            int qa = tid + i * 256;          // 0..511 quads
            int r  = qa >> 2, kq = qa & 3;
            int grow = row0 + r;
            int b = grow & 31, tl = grow >> 5;
            const float4 a = *(const float4*)(X + ((size_t)b * TT + t0 + tl) * DD + k0 + kq * 4);
            As[kq*4+0][r] = a.x; As[kq*4+1][r] = a.y;
            As[kq*4+2][r] = a.z; As[kq*4+3][r] = a.w;

            int qb = tid + i * 256;
            int kb = qb >> 5, c4 = qb & 31;
            *(float4*)&Bs[kb][c4*4] =
                *(const float4*)(Wm + (size_t)(k0 + kb) * G4H + col0 + c4 * 4);
        }
        __syncthreads();

        #pragma unroll
        for (int k = 0; k < 16; ++k) {
            float a[8], b[8];
            #pragma unroll
            for (int i = 0; i < 8; ++i) a[i] = As[k][ty*8 + i];
            #pragma unroll
            for (int j = 0; j < 8; ++j) b[j] = Bs[k][tx*8 + j];
            #pragma unroll
            for (int i = 0; i < 8; ++i)
                #pragma unroll
                for (int j = 0; j < 8; ++j) acc[i][j] += a[i] * b[j];
        }
        __syncthreads();
    }

    #pragma unroll
    for (int i = 0; i < 8; ++i) {
        int grow = row0 + ty*8 + i;
        float* dst = xw + (size_t)grow * G4H + col0 + tx*8;
        #pragma unroll
        for (int j = 0; j < 8; j += 4) {
            float4 v;
            v.x = acc[i][j+0] + bias[col0 + tx*8 + j + 0];
            v.y = acc[i][j+1] + bias[col0 + tx*8 + j + 1];
            v.z = acc[i][j+2] + bias[col0 + tx*8 + j + 2];
            v.w = acc[i][j+3] + bias[col0 + tx*8 + j + 3];
            *(float4*)(dst + j) = v;
        }
    }
}

// ---------------------------------------------------------------------------
// Phase B: persistent recurrent kernel, LDS-resident weights.
// Grid = 256 blocks x 256 threads. p = blockIdx%8 (batches 4p..4p+3),
// q = blockIdx/8 (hidden units 16q..16q+15 -> 64 gate columns, col_local=lane).
// Wave w (0..3) = K-slice of 128 (compute) = batch (reduce/update).
// Recurrent W slice (512 x 64 cols = 128 KiB) in LDS, loaded once.
// Sync-path changes this round:
//   (1) spin on the group counter with RELAXED loads (no per-poll
//       buffer_inv), then ONE acquire load after the spin exits — same
//       release/acquire pairing, ~100x fewer cache invalidates;
//   (2) xw for step t+1 prefetched at the top of step t (double-buffered
//       in a register) so HBM latency never sits on the rendezvous path.
// ---------------------------------------------------------------------------
__global__ __launch_bounds__(256, 1) void lstm_rec(
    const float* __restrict__ W,
    const float* __restrict__ h_init,
    const float* __restrict__ xw,
    float* __restrict__ out,
    float* __restrict__ c_ws,
    unsigned int* __restrict__ ctr,
    int t0, int nT)
{
    __shared__ float4 wlds[128][64];    // [k>>2][col_local] = w[4k..4k+3][col]
    __shared__ float  hbuf[4][HH];      // h for the 4 batches of this group
    __shared__ float  red[4][4][64];    // [kslice-wave][batch][lane]

    const int tid  = threadIdx.x;
    const int p    = blockIdx.x & 7;
    const int q    = blockIdx.x >> 3;
    const int w    = tid >> 6;          // wave id = K-slice (compute) = batch (reduce)
    const int lane = tid & 63;
    const int gi   = lane >> 4;
    const int u    = lane & 15;
    const int col  = gi * HH + q * 16 + u;   // this lane's global gate column

    // One-time: stage this block's recurrent W slice into LDS, k-packed.
    {
        const int cc = tid & 63;
        const int kq = tid >> 6;
        const int cg = (cc >> 4) * HH + q * 16 + (cc & 15);  // global col of cc
        const float* Wr = W + (size_t)DD * G4H + cg;
        #pragma unroll 4
        for (int i = 0; i < 32; ++i) {
            const int k4 = i * 4 + kq;          // 0..127
            float4 v;
            v.x = Wr[(size_t)(4 * k4 + 0) * G4H];
            v.y = Wr[(size_t)(4 * k4 + 1) * G4H];
            v.z = Wr[(size_t)(4 * k4 + 2) * G4H];
            v.w = Wr[(size_t)(4 * k4 + 3) * G4H];
            wlds[k4][cc] = v;
        }
    }
    __syncthreads();

    // c state: lanes 0..15 of wave w hold c[batch 4p+w][unit q*16+lane]
    float c = 0.f;
    if (t0 > 0 && lane < 16)
        c = c_ws[(size_t)(4 * p + w) * HH + q * 16 + lane];

    unsigned int* myctr = ctr + p * 64;
    const int k4b = w * 32;               // this wave's k-slice, in float4 units

    // Prologue: load xw for step 0.
    float xg = xw[((size_t)0 * BB + 4 * p + w) * G4H + col];

    for (int t = 0; t < nT; ++t) {
        const int gt = t0 + t;

        // Prefetch next step's x-part NOW (~one full step of latency cover).
        float xg_next = 0.f;
        if (t + 1 < nT)
            xg_next = xw[((size_t)(t + 1) * BB + 4 * p + w) * G4H + col];

        // Stage h(gt-1) into LDS: 4 x 512 floats, 2 float4 per thread.
        #pragma unroll
        for (int i = 0; i < 2; ++i) {
            int qd = tid + i * 256;          // 0..511
            int b  = qd >> 7, k4 = qd & 127;
            const float* src = (gt == 0)
                ? (h_init + k4 * 4)
                : (out + ((size_t)(4 * p + b) * TT + (gt - 1)) * HH + k4 * 4);
            *(float4*)&hbuf[b][k4 * 4] = *(const float4*)src;
        }
        __syncthreads();

        // K-slice partial dot: a[b] += sum_k w[k][col] * h[b][k], k in slice w.
        const float4* hb0 = (const float4*)&hbuf[0][w * 128];
        const float4* hb1 = (const float4*)&hbuf[1][w * 128];
        const float4* hb2 = (const float4*)&hbuf[2][w * 128];
        const float4* hb3 = (const float4*)&hbuf[3][w * 128];

        float a0 = 0.f, a1 = 0.f, a2 = 0.f, a3 = 0.f;
        #pragma unroll
        for (int j = 0; j < 32; ++j) {
            const float4 wv = wlds[k4b + j][lane];   // contiguous b128, no conflict
            const float4 h0 = hb0[j];                // uniform broadcast reads
            const float4 h1 = hb1[j];
            const float4 h2 = hb2[j];
            const float4 h3 = hb3[j];
            a0 += wv.x*h0.x; a0 += wv.y*h0.y; a0 += wv.z*h0.z; a0 += wv.w*h0.w;
            a1 += wv.x*h1.x; a1 += wv.y*h1.y; a1 += wv.z*h1.z; a1 += wv.w*h1.w;
            a2 += wv.x*h2.x; a2 += wv.y*h2.y; a2 += wv.z*h2.z; a2 += wv.w*h2.w;
            a3 += wv.x*h3.x; a3 += wv.y*h3.y; a3 += wv.z*h3.z; a3 += wv.w*h3.w;
        }

        red[w][0][lane] = a0; red[w][1][lane] = a1;
        red[w][2][lane] = a2; red[w][3][lane] = a3;
        __syncthreads();

        // Wave w reduces batch w across the 4 K-slices, adds x-part (+bias).
        float g = red[0][w][lane] + red[1][w][lane]
                + red[2][w][lane] + red[3][w][lane] + xg;

        // Gather f,i,o,g for unit ul; lanes 0..15 do the elementwise update.
        const int ul = lane & 15;
        const float fv = __shfl(g, ul);
        const float iv = __shfl(g, ul + 16);
        const float ov = __shfl(g, ul + 32);
        const float gv = __shfl(g, ul + 48);
        if (lane < 16) {
            const float sf = 1.f / (1.f + __expf(-fv));
            const float si = 1.f / (1.f + __expf(-iv));
            const float so = 1.f / (1.f + __expf(-ov));
            const float tg = 1.f - 2.f / (__expf(2.f * gv) + 1.f);
            c = sf * c + si * tg;
            const float tc = 1.f - 2.f / (__expf(2.f * c) + 1.f);
            const float h = so * tc;
            out[((size_t)(4 * p + w) * TT + gt) * HH + q * 16 + lane] = h;
        }

        // Per-group barrier, 32 blocks. The __syncthreads before arrival
        // drains every wave's stores (compiler emits vmcnt(0) before
        // s_barrier). Arrival: release add. Spin: RELAXED loads (no
        // per-poll invalidate). One ACQUIRE load after exit pairs with
        // the other blocks' release adds.
        __syncthreads();
        if (tid == 0) {
            __hip_atomic_fetch_add(myctr, 1u, __ATOMIC_RELEASE, __HIP_MEMORY_SCOPE_AGENT);
            const unsigned int tgt = 32u * (unsigned int)(gt + 1);
            while (__hip_atomic_load(myctr, __ATOMIC_RELAXED, __HIP_MEMORY_SCOPE_AGENT) < tgt) {}
            (void)__hip_atomic_load(myctr, __ATOMIC_ACQUIRE, __HIP_MEMORY_SCOPE_AGENT);
        }
        __syncthreads();

        xg = xg_next;
    }

    // Spill c state for the next chunk.
    if (lane < 16)
        c_ws[(size_t)(4 * p + w) * HH + q * 16 + lane] = c;
}

// ---------------------------------------------------------------------------
extern "C" void kernel_launch(void* const* d_in, const int* in_sizes, int n_in,
                              void* d_out, int out_size, void* d_ws, size_t ws_size,
                              hipStream_t stream) {
    const float* x      = (const float*)d_in[0];
    // d_in[1] = input_paddings (unused)
    const float* W      = (const float*)d_in[2];
    const float* bias   = (const float*)d_in[3];
    const float* h_init = (const float*)d_in[4];
    float* out = (float*)d_out;

    // Pick the largest chunk of T whose xw buffer fits in ws
    // (xw chunk = CT*32*2048*4 bytes; + 2KB counters + 64KB c-state).
    static const int cand[] = {2048, 1024, 512, 256, 128, 64, 32, 16, 8, 4};
    int CT = 4;
    for (int i = 0; i < 10; ++i) {
        if ((size_t)cand[i] * BB * G4H * 4 + 2048 + 65536 <= ws_size) { CT = cand[i]; break; }
    }
    const size_t xw_bytes = (size_t)CT * BB * G4H * 4;
    float*        xw   = (float*)d_ws;
    unsigned int* ctr  = (unsigned int*)((char*)d_ws + xw_bytes);
    float*        c_ws = (float*)((char*)d_ws + xw_bytes + 2048);

    for (int t0 = 0; t0 < TT; t0 += CT) {
        dim3 g(G4H / 128, CT * BB / 128);
        gemm_xw<<<g, 256, 0, stream>>>(x, W, bias, xw, t0, ctr);
        lstm_rec<<<256, 256, 0, stream>>>(W, h_init, xw, out, c_ws, ctr, t0, CT);
    }
}

// Round 6
// 12002.826 us; speedup vs baseline: 1.8024x; 1.6902x over previous
//
#include <hip/hip_runtime.h>
#include <math.h>

// Problem constants (reference: B,T,D,H = 32,2048,512,512)
#define BB   32
#define TT   2048
#define DD   512
#define HH   512
#define G4H  2048   // 4*H

// ---------------------------------------------------------------------------
// Phase A: xw[t_local*32 + b][col] = sum_d X[b][t0+t][d] * W[d][col] + bias[col]
// fp32 tiled GEMM: 128x128 block tile, 16 K-step, 256 threads, 8x8 microtile.
// Also zeroes the 8 group barrier counters on the first chunk (t0==0).
// ---------------------------------------------------------------------------
__global__ __launch_bounds__(256, 2) void gemm_xw(
    const float* __restrict__ X, const float* __restrict__ Wm,
    const float* __restrict__ bias, float* __restrict__ xw,
    int t0, unsigned int* __restrict__ ctr)
{
    if (t0 == 0 && blockIdx.x == 0 && blockIdx.y == 0 && threadIdx.x < 8)
        ctr[threadIdx.x * 64] = 0u;

    __shared__ float As[16][128];
    __shared__ float Bs[16][128];

    const int tid  = threadIdx.x;
    const int row0 = blockIdx.y * 128;   // rows: (t_local, b) t-major
    const int col0 = blockIdx.x * 128;
    const int tx = tid & 15;
    const int ty = tid >> 4;

    float acc[8][8];
    #pragma unroll
    for (int i = 0; i < 8; ++i)
        #pragma unroll
        for (int j = 0; j < 8; ++j) acc[i][j] = 0.f;

    for (int k0 = 0; k0 < DD; k0 += 16) {
        #pragma unroll
        for (int i = 0; i < 2; ++i) {
            int qa = tid + i * 256;          // 0..511 quads
            int r  = qa >> 2, kq = qa & 3;
            int grow = row0 + r;
            int b = grow & 31, tl = grow >> 5;
            const float4 a = *(const float4*)(X + ((size_t)b * TT + t0 + tl) * DD + k0 + kq * 4);
            As[kq*4+0][r] = a.x; As[kq*4+1][r] = a.y;
            As[kq*4+2][r] = a.z; As[kq*4+3][r] = a.w;

            int qb = tid + i * 256;
            int kb = qb >> 5, c4 = qb & 31;
            *(float4*)&Bs[kb][c4*4] =
                *(const float4*)(Wm + (size_t)(k0 + kb) * G4H + col0 + c4 * 4);
        }
        __syncthreads();

        #pragma unroll
        for (int k = 0; k < 16; ++k) {
            float a[8], b[8];
            #pragma unroll
            for (int i = 0; i < 8; ++i) a[i] = As[k][ty*8 + i];
            #pragma unroll
            for (int j = 0; j < 8; ++j) b[j] = Bs[k][tx*8 + j];
            #pragma unroll
            for (int i = 0; i < 8; ++i)
                #pragma unroll
                for (int j = 0; j < 8; ++j) acc[i][j] += a[i] * b[j];
        }
        __syncthreads();
    }

    #pragma unroll
    for (int i = 0; i < 8; ++i) {
        int grow = row0 + ty*8 + i;
        float* dst = xw + (size_t)grow * G4H + col0 + tx*8;
        #pragma unroll
        for (int j = 0; j < 8; j += 4) {
            float4 v;
            v.x = acc[i][j+0] + bias[col0 + tx*8 + j + 0];
            v.y = acc[i][j+1] + bias[col0 + tx*8 + j + 1];
            v.z = acc[i][j+2] + bias[col0 + tx*8 + j + 2];
            v.w = acc[i][j+3] + bias[col0 + tx*8 + j + 3];
            *(float4*)(dst + j) = v;
        }
    }
}

// ---------------------------------------------------------------------------
// Phase B: persistent recurrent kernel, LDS-resident weights.
// Grid = 256 blocks x 256 threads. p = blockIdx%8 (batches 4p..4p+3),
// q = blockIdx/8 (hidden units 16q..16q+15 -> 64 gate columns, col_local=lane).
// Wave w (0..3) = K-slice of 128 (compute) = batch (reduce/update).
// Recurrent W slice (512 x 64 cols = 128 KiB) in LDS, loaded once.
//
// Sync protocol this round: ZERO cache-maintenance ops. All cross-block
// traffic (h exchange + barrier counter) uses RELAXED atomics at SYSTEM
// scope -> sc0/sc1 instructions that operate directly at the common
// coherence point (L3), bypassing the non-coherent per-XCD L1/L2. No
// release/acquire means no buffer_wbl2 / buffer_inv cache walks per step
// (the suspected ~8 us/step cost in R1-R5). Physical ordering argument:
// __syncthreads drains each wave's system-scope h-stores (vmcnt(0)) so
// they are ack'd at L3 BEFORE tid0 issues the counter add; readers
// observe the counter at L3, and their subsequent system-scope loads
// (compiler-fenced by an empty asm memory clobber) read L3 afterwards.
// Correct regardless of XCD placement (Guideline 16).
// ---------------------------------------------------------------------------
__global__ __launch_bounds__(256, 1) void lstm_rec(
    const float* __restrict__ W,
    const float* __restrict__ h_init,
    const float* __restrict__ xw,
    float* out,
    float* __restrict__ c_ws,
    unsigned int* ctr,
    int t0, int nT)
{
    __shared__ float4 wlds[128][64];    // [k>>2][col_local] = w[4k..4k+3][col]
    __shared__ float  hbuf[4][HH];      // h for the 4 batches of this group
    __shared__ float  red[4][4][64];    // [kslice-wave][batch][lane]

    const int tid  = threadIdx.x;
    const int p    = blockIdx.x & 7;
    const int q    = blockIdx.x >> 3;
    const int w    = tid >> 6;          // wave id = K-slice (compute) = batch (reduce)
    const int lane = tid & 63;
    const int gi   = lane >> 4;
    const int u    = lane & 15;
    const int col  = gi * HH + q * 16 + u;   // this lane's global gate column

    // One-time: stage this block's recurrent W slice into LDS, k-packed.
    {
        const int cc = tid & 63;
        const int kq = tid >> 6;
        const int cg = (cc >> 4) * HH + q * 16 + (cc & 15);  // global col of cc
        const float* Wr = W + (size_t)DD * G4H + cg;
        #pragma unroll 4
        for (int i = 0; i < 32; ++i) {
            const int k4 = i * 4 + kq;          // 0..127
            float4 v;
            v.x = Wr[(size_t)(4 * k4 + 0) * G4H];
            v.y = Wr[(size_t)(4 * k4 + 1) * G4H];
            v.z = Wr[(size_t)(4 * k4 + 2) * G4H];
            v.w = Wr[(size_t)(4 * k4 + 3) * G4H];
            wlds[k4][cc] = v;
        }
    }
    __syncthreads();

    // c state: lanes 0..15 of wave w hold c[batch 4p+w][unit q*16+lane]
    float c = 0.f;
    if (t0 > 0 && lane < 16)
        c = c_ws[(size_t)(4 * p + w) * HH + q * 16 + lane];

    unsigned int* myctr = ctr + p * 64;
    const int k4b = w * 32;               // this wave's k-slice, in float4 units

    // Prologue: load xw for step 0.
    float xg = xw[((size_t)0 * BB + 4 * p + w) * G4H + col];

    for (int t = 0; t < nT; ++t) {
        const int gt = t0 + t;

        // Prefetch next step's x-part NOW (~one full step of latency cover).
        float xg_next = 0.f;
        if (t + 1 < nT)
            xg_next = xw[((size_t)(t + 1) * BB + 4 * p + w) * G4H + col];

        // Stage h(gt-1) into LDS via system-scope relaxed loads (read fresh
        // L3 directly; no acquire/inv needed). Lane-consecutive -> coalesced.
        if (gt == 0) {
            #pragma unroll
            for (int i = 0; i < 8; ++i) {
                const int e = i * 256 + tid;     // 0..2047
                hbuf[e >> 9][e & 511] = h_init[e & 511];
            }
        } else {
            #pragma unroll
            for (int i = 0; i < 8; ++i) {
                const int e   = i * 256 + tid;   // 0..2047
                const int b   = e >> 9;
                const int idx = e & 511;
                float v = __hip_atomic_load(
                    &out[((size_t)(4 * p + b) * TT + (gt - 1)) * HH + idx],
                    __ATOMIC_RELAXED, __HIP_MEMORY_SCOPE_SYSTEM);
                hbuf[b][idx] = v;
            }
        }
        __syncthreads();

        // K-slice partial dot: a[b] += sum_k w[k][col] * h[b][k], k in slice w.
        const float4* hb0 = (const float4*)&hbuf[0][w * 128];
        const float4* hb1 = (const float4*)&hbuf[1][w * 128];
        const float4* hb2 = (const float4*)&hbuf[2][w * 128];
        const float4* hb3 = (const float4*)&hbuf[3][w * 128];

        float a0 = 0.f, a1 = 0.f, a2 = 0.f, a3 = 0.f;
        #pragma unroll
        for (int j = 0; j < 32; ++j) {
            const float4 wv = wlds[k4b + j][lane];   // contiguous b128, no conflict
            const float4 h0 = hb0[j];                // uniform broadcast reads
            const float4 h1 = hb1[j];
            const float4 h2 = hb2[j];
            const float4 h3 = hb3[j];
            a0 += wv.x*h0.x; a0 += wv.y*h0.y; a0 += wv.z*h0.z; a0 += wv.w*h0.w;
            a1 += wv.x*h1.x; a1 += wv.y*h1.y; a1 += wv.z*h1.z; a1 += wv.w*h1.w;
            a2 += wv.x*h2.x; a2 += wv.y*h2.y; a2 += wv.z*h2.z; a2 += wv.w*h2.w;
            a3 += wv.x*h3.x; a3 += wv.y*h3.y; a3 += wv.z*h3.z; a3 += wv.w*h3.w;
        }

        red[w][0][lane] = a0; red[w][1][lane] = a1;
        red[w][2][lane] = a2; red[w][3][lane] = a3;
        __syncthreads();

        // Wave w reduces batch w across the 4 K-slices, adds x-part (+bias).
        float g = red[0][w][lane] + red[1][w][lane]
                + red[2][w][lane] + red[3][w][lane] + xg;

        // Gather f,i,o,g for unit ul; lanes 0..15 do the elementwise update.
        const int ul = lane & 15;
        const float fv = __shfl(g, ul);
        const float iv = __shfl(g, ul + 16);
        const float ov = __shfl(g, ul + 32);
        const float gv = __shfl(g, ul + 48);
        if (lane < 16) {
            const float sf = 1.f / (1.f + __expf(-fv));
            const float si = 1.f / (1.f + __expf(-iv));
            const float so = 1.f / (1.f + __expf(-ov));
            const float tg = 1.f - 2.f / (__expf(2.f * gv) + 1.f);
            c = sf * c + si * tg;
            const float tc = 1.f - 2.f / (__expf(2.f * c) + 1.f);
            const float h = so * tc;
            // System-scope relaxed store: lands at L3, visible to all XCDs,
            // no wbl2 cache walk.
            __hip_atomic_store(
                &out[((size_t)(4 * p + w) * TT + gt) * HH + q * 16 + lane],
                h, __ATOMIC_RELAXED, __HIP_MEMORY_SCOPE_SYSTEM);
        }

        // Per-group barrier, 32 blocks, zero cache-maintenance:
        // __syncthreads drains every wave's system-scope h stores (vmcnt(0)
        // -> ack'd at L3), then tid0 bumps the group counter (relaxed
        // system RMW at L3) and spins on relaxed system loads.
        __syncthreads();
        if (tid == 0) {
            __hip_atomic_fetch_add(myctr, 1u, __ATOMIC_RELAXED, __HIP_MEMORY_SCOPE_SYSTEM);
            const unsigned int tgt = 32u * (unsigned int)(gt + 1);
            while (__hip_atomic_load(myctr, __ATOMIC_RELAXED, __HIP_MEMORY_SCOPE_SYSTEM) < tgt) {}
        }
        // Compiler-level fence only (no HW op): keeps next step's h loads
        // from being hoisted above the spin.
        asm volatile("" ::: "memory");
        __syncthreads();

        xg = xg_next;
    }

    // Spill c state for the next chunk (read at next dispatch; kernel
    // boundary provides the coherence).
    if (lane < 16)
        c_ws[(size_t)(4 * p + w) * HH + q * 16 + lane] = c;
}

// ---------------------------------------------------------------------------
extern "C" void kernel_launch(void* const* d_in, const int* in_sizes, int n_in,
                              void* d_out, int out_size, void* d_ws, size_t ws_size,
                              hipStream_t stream) {
    const float* x      = (const float*)d_in[0];
    // d_in[1] = input_paddings (unused)
    const float* W      = (const float*)d_in[2];
    const float* bias   = (const float*)d_in[3];
    const float* h_init = (const float*)d_in[4];
    float* out = (float*)d_out;

    // Pick the largest chunk of T whose xw buffer fits in ws
    // (xw chunk = CT*32*2048*4 bytes; + 2KB counters + 64KB c-state).
    static const int cand[] = {2048, 1024, 512, 256, 128, 64, 32, 16, 8, 4};
    int CT = 4;
    for (int i = 0; i < 10; ++i) {
        if ((size_t)cand[i] * BB * G4H * 4 + 2048 + 65536 <= ws_size) { CT = cand[i]; break; }
    }
    const size_t xw_bytes = (size_t)CT * BB * G4H * 4;
    float*        xw   = (float*)d_ws;
    unsigned int* ctr  = (unsigned int*)((char*)d_ws + xw_bytes);
    float*        c_ws = (float*)((char*)d_ws + xw_bytes + 2048);

    for (int t0 = 0; t0 < TT; t0 += CT) {
        dim3 g(G4H / 128, CT * BB / 128);
        gemm_xw<<<g, 256, 0, stream>>>(x, W, bias, xw, t0, ctr);
        lstm_rec<<<256, 256, 0, stream>>>(W, h_init, xw, out, c_ws, ctr, t0, CT);
    }
}